// Round 8
// baseline (203.659 us; speedup 1.0000x reference)
//
#include <hip/hip_runtime.h>

typedef __attribute__((ext_vector_type(8))) short bf16x8;
typedef __attribute__((ext_vector_type(4))) float f32x4;

#define D_MODEL 1024
#define NHEADS 16
#define HDIM 64
#define SEQ 2048
#define BATCH 2
#define MROWS (BATCH*SEQ)   // 4096
#define NQKV (3*D_MODEL)    // 3072
// softmax in exp2 domain: fold 1/sqrt(64) * log2(e) into Q scale
#define QSCALE 0.1803368801111204f
#define LPAD 72    // vtrans LDS row stride (shorts)
#define CSTR 144   // gemm C-tile LDS row stride (shorts)

__device__ __forceinline__ unsigned short f2bf(float f) {
  unsigned int u = __float_as_uint(f);
  u += 0x7FFF + ((u >> 16) & 1);   // RNE
  return (unsigned short)(u >> 16);
}
__device__ __forceinline__ unsigned int pack2bf(float a, float b) {
#if __has_builtin(__builtin_amdgcn_cvt_pk_bf16_f32)
  auto r = __builtin_amdgcn_cvt_pk_bf16_f32(a, b);
  unsigned int u; __builtin_memcpy(&u, &r, 4);
  return u;
#else
  return ((unsigned int)f2bf(b) << 16) | (unsigned int)f2bf(a);
#endif
}

// async global->LDS, 16B per lane. Dest = wave-uniform base + lane*16.
__device__ __forceinline__ void gload16(const void* g, void* l) {
  __builtin_amdgcn_global_load_lds((const __attribute__((address_space(1))) void*)g,
                                   (__attribute__((address_space(3))) void*)l, 16, 0, 0);
}

// fused fp32 -> bf16 conversion for x, Wqkv, Wo (one launch)
#define N4_X     1048576
#define N4_WQKV   786432
#define N4_WO     262144
__global__ void cvt_all_kernel(const float4* __restrict__ x,
                               const float4* __restrict__ wqkv,
                               const float4* __restrict__ wo,
                               ushort4* __restrict__ xb,
                               ushort4* __restrict__ wqkvb,
                               ushort4* __restrict__ wob) {
  int i = blockIdx.x * blockDim.x + threadIdx.x;
  const float4* s; ushort4* d; int j;
  if (i < N4_X)                { s = x;    d = xb;    j = i; }
  else if (i < N4_X + N4_WQKV) { s = wqkv; d = wqkvb; j = i - N4_X; }
  else                         { s = wo;   d = wob;   j = i - (N4_X + N4_WQKV); }
  float4 v = s[j];
  ushort4 o;
  o.x = f2bf(v.x); o.y = f2bf(v.y); o.z = f2bf(v.z); o.w = f2bf(v.w);
  d[j] = o;
}

// C[M,N] = A[M,K](bf16) @ B[N,K]^T(bf16) + bias
// Single-barrier double-buffered staging: loads for k0+32 issued right AFTER
// the barrier, drained by the NEXT barrier (full stage of latency cover).
// LDS placement XOR-swizzled so ds_read_b128 fragments are conflict-free.
// MODE 0: LDS-staged epilogue -> coalesced 16B stores into Q/K/V bf16
// MODE 1: plain fp32 store (output projection)
template<int MODE, int BM>
__global__ __launch_bounds__(256) void gemm_bt_kernel(
    const unsigned short* __restrict__ A,
    const unsigned short* __restrict__ Bm,
    const float* __restrict__ bias,
    float* __restrict__ outF,
    unsigned short* __restrict__ Qb,
    unsigned short* __restrict__ Kb,
    unsigned short* __restrict__ Vb,
    int M, int N, int K)
{
  constexpr int MI = BM / 32;
  constexpr int STG = BM*32 + 128*32;     // shorts per stage (A+B)
  constexpr int SHSZ = (MODE == 0 && 128*CSTR > 2*STG) ? 128*CSTR : 2*STG;
  __shared__ __align__(16) unsigned short Sh[SHSZ];
  const int tid = threadIdx.x;
  const int wave = tid >> 6, lane = tid & 63;
  const int lm = lane & 15, quad = lane >> 4;
  const int wm = (wave >> 1) * (BM/2), wn = (wave & 1) * 64;
  const int m0 = blockIdx.y * BM, n0 = blockIdx.x * 128;

  f32x4 acc[MI][4] = {};

  auto stage_in = [&](int k0, int sb) {
    unsigned short* As = Sh + sb*STG;
    unsigned short* Bs = As + BM*32;
#pragma unroll
    for (int i = 0; i < BM/64; i++) {
      int ch = i*256 + tid;
      int r = ch >> 2, cg = (ch & 3) ^ ((r >> 1) & 3);   // swizzled source chunk
      gload16(&A[(size_t)(m0 + r) * K + k0 + cg*8], &As[ch*8]);
    }
#pragma unroll
    for (int i = 0; i < 2; i++) {
      int ch = i*256 + tid;
      int r = ch >> 2, cg = (ch & 3) ^ ((r >> 1) & 3);
      gload16(&Bm[(size_t)(n0 + r) * K + k0 + cg*8], &Bs[ch*8]);
    }
  };

  stage_in(0, 0);
  for (int k0 = 0; k0 < K; k0 += 32) {
    const int cur = (k0 >> 5) & 1;
    __syncthreads();                       // drains staged loads for this stage
    if (k0 + 32 < K) stage_in(k0 + 32, cur ^ 1);
    const unsigned short* As = Sh + cur*STG;
    const unsigned short* Bs = As + BM*32;
    bf16x8 af[MI], bfr[4];
#pragma unroll
    for (int mi = 0; mi < MI; mi++) {
      int r = wm + mi*16 + lm;
      af[mi] = *(const bf16x8*)&As[(r*4 + (quad ^ ((r >> 1) & 3))) * 8];
    }
#pragma unroll
    for (int ni = 0; ni < 4; ni++) {
      int r = wn + ni*16 + lm;
      bfr[ni] = *(const bf16x8*)&Bs[(r*4 + (quad ^ ((r >> 1) & 3))) * 8];
    }
#pragma unroll
    for (int mi = 0; mi < MI; mi++)
#pragma unroll
      for (int ni = 0; ni < 4; ni++)
        acc[mi][ni] = __builtin_amdgcn_mfma_f32_16x16x32_bf16(af[mi], bfr[ni], acc[mi][ni], 0, 0, 0);
  }

  if (MODE == 1) {
#pragma unroll
    for (int mi = 0; mi < MI; mi++)
#pragma unroll
      for (int ni = 0; ni < 4; ni++)
#pragma unroll
        for (int r = 0; r < 4; r++) {
          int row = m0 + wm + mi*16 + quad*4 + r;   // C/D: row=(lane>>4)*4+reg
          int col = n0 + wn + ni*16 + lm;           //      col=lane&15
          outF[(size_t)row * N + col] = acc[mi][ni][r] + bias[col];
        }
  } else {
    __syncthreads();
#pragma unroll
    for (int mi = 0; mi < MI; mi++)
#pragma unroll
      for (int ni = 0; ni < 4; ni++)
#pragma unroll
        for (int r = 0; r < 4; r++) {
          int row_l = wm + mi*16 + quad*4 + r;
          int col_l = wn + ni*16 + lm;
          int col = n0 + col_l;
          float v = acc[mi][ni][r] + bias[col];
          if (((col % 192) >> 6) == 0) v *= QSCALE;
          Sh[row_l*CSTR + col_l] = f2bf(v);
        }
    __syncthreads();
#pragma unroll
    for (int i = 0; i < BM*16/256; i++) {
      int lin = i*256 + tid;
      int row_l = lin >> 4, cc = (lin & 15) * 8;
      uint4 d = *(const uint4*)&Sh[row_l*CSTR + cc];
      int row = m0 + row_l, col = n0 + cc;
      int b = row >> 11, s = row & (SEQ - 1);
      int h = col / 192, rr = col - h*192;
      int ty = rr >> 6, e = rr & 63;
      size_t dsti = ((size_t)(b*NHEADS + h)*SEQ + s)*HDIM + e;
      unsigned short* dst = (ty == 0) ? Qb : (ty == 1) ? Kb : Vb;
      *(uint4*)&dst[dsti] = d;
    }
  }
}

// V [bh][s][e] -> V^T [bh][e][s], 64x64 tiles via LDS
__global__ __launch_bounds__(256) void vtrans_kernel(
    const unsigned short* __restrict__ Vb, unsigned short* __restrict__ VTb) {
  __shared__ __align__(16) unsigned short T[64*LPAD];
  const int bh = blockIdx.y, s0 = blockIdx.x * 64;
  const int tid = threadIdx.x;
#pragma unroll
  for (int i = 0; i < 2; i++) {
    int ch = i*256 + tid;
    int r = ch >> 3, c = (ch & 7) * 8;
    *(uint4*)&T[r*LPAD + c] = *(const uint4*)&Vb[((size_t)bh*SEQ + s0 + r)*HDIM + c];
  }
  __syncthreads();
#pragma unroll
  for (int i = 0; i < 2; i++) {
    int ch = i*256 + tid;
    int e = ch >> 3, c = (ch & 7) * 8;
    unsigned short tmp[8];
#pragma unroll
    for (int j = 0; j < 8; j++) tmp[j] = T[(c + j)*LPAD + e];
    *(uint4*)&VTb[((size_t)bh*HDIM + e)*SEQ + s0 + c] = *(const uint4*)tmp;
  }
}

// Causal flash attention: 512-thread blocks (8 waves), ONE 128-query tile per
// block. 512 blocks = 4096 waves (~16/CU, 2 blocks/CU resident; LDS 48KB
// allows 3) -> doubles VALU overlap vs r7's 256 paired blocks at identical
// work/traffic. Balance via dispatch order: heavy tiles (t=15, 32 stages)
// first, light tiles backfill. K/V staged in LDS shared by 8 waves;
// single-barrier double-buffered staging (stage s+1 issued right after the
// barrier of stage s, drained at the next barrier). XOR-swizzled LDS chunks
// for conflict-free ds_read_b128.
__global__ __launch_bounds__(512) void flash_attn_kernel(
    const unsigned short* __restrict__ Qb,
    const unsigned short* __restrict__ Kb,
    const unsigned short* __restrict__ VTb,
    unsigned short* __restrict__ Ob)
{
  const int tid = threadIdx.x;
  const int wave = tid >> 6, lane = tid & 63;
  const int lm = lane & 15, quad = lane >> 4;
  const int bx = blockIdx.x;                  // 0..31 (fastest dispatch dim)
  const int bh = (bx & 7) * 4 + (bx >> 3);    // XCD i serves bh {4i..4i+3}
  const int t  = 15 - blockIdx.y;             // heavy tiles dispatched first
  const int nkt = 2 * (t + 1);                // 64-key stages

  __shared__ __align__(16) unsigned short Ks[2][64*64];  // [buf][key][e] swizzled
  __shared__ __align__(16) unsigned short Vs[2][64*64];  // [buf][e][key] swizzled
  __shared__ __align__(16) unsigned short Ps[8][16*64];  // per-wave P, swizzled

  const unsigned short* Qbh  = Qb  + (size_t)bh*SEQ*HDIM;
  const unsigned short* Kbh  = Kb  + (size_t)bh*SEQ*HDIM;
  const unsigned short* VTbh = VTb + (size_t)bh*HDIM*SEQ;
  unsigned short* Pw = &Ps[wave][lm * 64];
  const int sw = lm & 7;

  // staging: 512 threads, 1 chunk K + 1 chunk V each; source chunk index
  // XOR-permuted within each 128B row so LDS slot tid holds chunk cg^(r&7).
  const int st_r = tid >> 3;
  const int st_cg = (tid & 7) ^ (st_r & 7);
  auto stage_in = [&](int k0, int sb) {
    gload16(&Kbh[(size_t)(k0 + st_r)*HDIM + st_cg*8], &Ks[sb][tid*8]);
    gload16(&VTbh[(size_t)st_r*SEQ + k0 + st_cg*8],   &Vs[sb][tid*8]);
  };

  const int rowq = t*128 + wave*16;
  const int query = rowq + lm;
  bf16x8 qf[2];
#pragma unroll
  for (int kc = 0; kc < 2; kc++)
    qf[kc] = *(const bf16x8*)&Qbh[(size_t)query*HDIM + kc*32 + quad*8];

  f32x4 o[4] = {};
  float m_run = -1e30f, l_run = 0.f;

  stage_in(0, 0);
  for (int s = 0; s < nkt; s++) {
    const int k0 = s * 64;
    const int cur = s & 1;
    __syncthreads();                     // staged loads for s drained here
    if (s + 1 < nkt) stage_in(k0 + 64, cur ^ 1);  // in flight across this stage

    // S^T = K @ Q^T  (rows = keys, cols = queries)
    f32x4 sc[4] = {};
#pragma unroll
    for (int kc = 0; kc < 2; kc++)
#pragma unroll
      for (int mi = 0; mi < 4; mi++) {
        int r = mi*16 + lm, cc = kc*4 + quad;
        bf16x8 kf = *(const bf16x8*)&Ks[cur][(r*8 + (cc ^ (r & 7))) * 8];
        sc[mi] = __builtin_amdgcn_mfma_f32_16x16x32_bf16(kf, qf[kc], sc[mi], 0, 0, 0);
      }

    if (k0 + 63 > rowq) {                // causal mask (wave-uniform branch)
#pragma unroll
      for (int mi = 0; mi < 4; mi++)
#pragma unroll
        for (int r = 0; r < 4; r++) {
          int key = k0 + mi*16 + quad*4 + r;
          if (key > query) sc[mi][r] = -1e30f;
        }
    }

    // online softmax (exp2 domain); lane's 16 values all belong to query lm
    float mx = sc[0][0];
#pragma unroll
    for (int mi = 0; mi < 4; mi++)
#pragma unroll
      for (int r = 0; r < 4; r++) mx = fmaxf(mx, sc[mi][r]);
    mx = fmaxf(mx, __shfl_xor(mx, 16, 64));
    mx = fmaxf(mx, __shfl_xor(mx, 32, 64));
    float mnew = fmaxf(m_run, mx);
    float alpha = exp2f(m_run - mnew);
    float p[4][4];
    float rs = 0.f;
#pragma unroll
    for (int mi = 0; mi < 4; mi++)
#pragma unroll
      for (int r = 0; r < 4; r++) {
        p[mi][r] = exp2f(sc[mi][r] - mnew);
        rs += p[mi][r];
      }
    rs += __shfl_xor(rs, 16, 64);
    rs += __shfl_xor(rs, 32, 64);
    l_run = l_run * alpha + rs;
    m_run = mnew;
#pragma unroll
    for (int ei = 0; ei < 4; ei++)
#pragma unroll
      for (int r = 0; r < 4; r++) o[ei][r] *= alpha;

    // P -> wave-private LDS (swizzled b64 writes, 2-way max = free)
#pragma unroll
    for (int mi = 0; mi < 4; mi++) {
      uint2 u;
      u.x = pack2bf(p[mi][0], p[mi][1]);
      u.y = pack2bf(p[mi][2], p[mi][3]);
      int chunk = (2*mi + (quad >> 1)) ^ sw;
      *(uint2*)&Pw[chunk*8 + (quad & 1)*4] = u;
    }
    asm volatile("s_waitcnt lgkmcnt(0)" ::: "memory");  // same-wave cross-lane

    // O^T += V^T @ P^T
#pragma unroll
    for (int kc = 0; kc < 2; kc++) {
      bf16x8 pf = *(const bf16x8*)&Pw[((kc*4 + quad) ^ sw) * 8];
#pragma unroll
      for (int ei = 0; ei < 4; ei++) {
        int e = ei*16 + lm, cc = kc*4 + quad;
        bf16x8 vf = *(const bf16x8*)&Vs[cur][(e*8 + (cc ^ (e & 7))) * 8];
        o[ei] = __builtin_amdgcn_mfma_f32_16x16x32_bf16(vf, pf, o[ei], 0, 0, 0);
      }
    }
  }

  // epilogue: O^T/l -> Ob[bh][s][e] (bf16), 8B packed stores
  float inv = 1.0f / l_run;
  size_t obase = ((size_t)bh*SEQ + query) * HDIM;
#pragma unroll
  for (int ei = 0; ei < 4; ei++) {
    uint2 u;
    u.x = pack2bf(o[ei][0]*inv, o[ei][1]*inv);
    u.y = pack2bf(o[ei][2]*inv, o[ei][3]*inv);
    *(uint2*)&Ob[obase + ei*16 + quad*4] = u;
  }
}

extern "C" void kernel_launch(void* const* d_in, const int* in_sizes, int n_in,
                              void* d_out, int out_size, void* d_ws, size_t ws_size,
                              hipStream_t stream) {
  const float* x    = (const float*)d_in[0];
  const float* Wqkv = (const float*)d_in[1];
  const float* bqkv = (const float*)d_in[2];
  const float* Wo   = (const float*)d_in[3];
  const float* bo   = (const float*)d_in[4];
  float* out = (float*)d_out;

  char* ws = (char*)d_ws;
  unsigned short* Xbf    = (unsigned short*)(ws);              // 8 MiB (-> VTb)
  unsigned short* Wqkvbf = (unsigned short*)(ws + 8388608);    // 6 MiB
  unsigned short* Wobf   = (unsigned short*)(ws + 14680064);   // 2 MiB
  unsigned short* Qb     = (unsigned short*)(ws + 16777216);   // 8 MiB [B,H,S,hd]
  unsigned short* Kb     = (unsigned short*)(ws + 25165824);   // 8 MiB [B,H,S,hd]
  unsigned short* Vb     = (unsigned short*)(ws + 33554432);   // 8 MiB [B,H,S,hd]
  unsigned short* Ob     = (unsigned short*)(ws + 41943040);   // 8 MiB [B,H,S,hd]
  unsigned short* VTb    = Xbf;   // Xbf dead after GEMM1 (stream-ordered)

  cvt_all_kernel<<<8192, 256, 0, stream>>>(
      (const float4*)x, (const float4*)Wqkv, (const float4*)Wo,
      (ushort4*)Xbf, (ushort4*)Wqkvbf, (ushort4*)Wobf);

  gemm_bt_kernel<0,128><<<dim3(24, 32), 256, 0, stream>>>(
      Xbf, Wqkvbf, bqkv, nullptr, Qb, Kb, Vb, MROWS, NQKV, D_MODEL);

  vtrans_kernel<<<dim3(32, 32), 256, 0, stream>>>(Vb, VTb);

  flash_attn_kernel<<<dim3(32, 16), 512, 0, stream>>>(Qb, Kb, VTb, Ob);

  gemm_bt_kernel<1,64><<<dim3(8, 64), 256, 0, stream>>>(
      Ob, Wobf, bo, out, nullptr, nullptr, nullptr, MROWS, D_MODEL, D_MODEL);
}

// Round 9
// 185.753 us; speedup vs baseline: 1.0964x; 1.0964x over previous
//
#include <hip/hip_runtime.h>

typedef __attribute__((ext_vector_type(8))) short bf16x8;
typedef __attribute__((ext_vector_type(4))) float f32x4;

#define D_MODEL 1024
#define NHEADS 16
#define HDIM 64
#define SEQ 2048
#define BATCH 2
#define MROWS (BATCH*SEQ)   // 4096
#define NQKV (3*D_MODEL)    // 3072
// softmax in exp2 domain: fold 1/sqrt(64) * log2(e) into Q scale
#define QSCALE 0.1803368801111204f
#define CSTR 144   // gemm C-tile LDS row stride (shorts)

__device__ __forceinline__ unsigned short f2bf(float f) {
  unsigned int u = __float_as_uint(f);
  u += 0x7FFF + ((u >> 16) & 1);   // RNE
  return (unsigned short)(u >> 16);
}
__device__ __forceinline__ unsigned int pack2bf(float a, float b) {
#if __has_builtin(__builtin_amdgcn_cvt_pk_bf16_f32)
  auto r = __builtin_amdgcn_cvt_pk_bf16_f32(a, b);
  unsigned int u; __builtin_memcpy(&u, &r, 4);
  return u;
#else
  return ((unsigned int)f2bf(b) << 16) | (unsigned int)f2bf(a);
#endif
}

// async global->LDS, 16B per lane. Dest = wave-uniform base + lane*16.
__device__ __forceinline__ void gload16(const void* g, void* l) {
  __builtin_amdgcn_global_load_lds((const __attribute__((address_space(1))) void*)g,
                                   (__attribute__((address_space(3))) void*)l, 16, 0, 0);
}

// fused fp32 -> bf16 conversion for x, Wqkv, Wo (one launch)
#define N4_X     1048576
#define N4_WQKV   786432
#define N4_WO     262144
__global__ void cvt_all_kernel(const float4* __restrict__ x,
                               const float4* __restrict__ wqkv,
                               const float4* __restrict__ wo,
                               ushort4* __restrict__ xb,
                               ushort4* __restrict__ wqkvb,
                               ushort4* __restrict__ wob) {
  int i = blockIdx.x * blockDim.x + threadIdx.x;
  const float4* s; ushort4* d; int j;
  if (i < N4_X)                { s = x;    d = xb;    j = i; }
  else if (i < N4_X + N4_WQKV) { s = wqkv; d = wqkvb; j = i - N4_X; }
  else                         { s = wo;   d = wob;   j = i - (N4_X + N4_WQKV); }
  float4 v = s[j];
  ushort4 o;
  o.x = f2bf(v.x); o.y = f2bf(v.y); o.z = f2bf(v.z); o.w = f2bf(v.w);
  d[j] = o;
}

// C[M,N] = A[M,K](bf16) @ B[N,K]^T(bf16) + bias
// Single-barrier double-buffered staging; XOR-swizzled LDS chunks.
// MODE 0: LDS-staged epilogue -> Q/K coalesced [bh][s][e] + V TRANSPOSED
//         [bh][e][s] directly (vtrans kernel eliminated). Q pre-scaled.
// MODE 1: plain fp32 store (output projection)
template<int MODE, int BM>
__global__ __launch_bounds__(256) void gemm_bt_kernel(
    const unsigned short* __restrict__ A,
    const unsigned short* __restrict__ Bm,
    const float* __restrict__ bias,
    float* __restrict__ outF,
    unsigned short* __restrict__ Qb,
    unsigned short* __restrict__ Kb,
    unsigned short* __restrict__ VTb,
    int M, int N, int K)
{
  constexpr int MI = BM / 32;
  constexpr int STG = BM*32 + 128*32;     // shorts per stage (A+B)
  constexpr int SHSZ = (MODE == 0 && 128*CSTR > 2*STG) ? 128*CSTR : 2*STG;
  __shared__ __align__(16) unsigned short Sh[SHSZ];
  const int tid = threadIdx.x;
  const int wave = tid >> 6, lane = tid & 63;
  const int lm = lane & 15, quad = lane >> 4;
  const int wm = (wave >> 1) * (BM/2), wn = (wave & 1) * 64;
  const int m0 = blockIdx.y * BM, n0 = blockIdx.x * 128;

  f32x4 acc[MI][4] = {};

  auto stage_in = [&](int k0, int sb) {
    unsigned short* As = Sh + sb*STG;
    unsigned short* Bs = As + BM*32;
#pragma unroll
    for (int i = 0; i < BM/64; i++) {
      int ch = i*256 + tid;
      int r = ch >> 2, cg = (ch & 3) ^ ((r >> 1) & 3);
      gload16(&A[(size_t)(m0 + r) * K + k0 + cg*8], &As[ch*8]);
    }
#pragma unroll
    for (int i = 0; i < 2; i++) {
      int ch = i*256 + tid;
      int r = ch >> 2, cg = (ch & 3) ^ ((r >> 1) & 3);
      gload16(&Bm[(size_t)(n0 + r) * K + k0 + cg*8], &Bs[ch*8]);
    }
  };

  stage_in(0, 0);
  for (int k0 = 0; k0 < K; k0 += 32) {
    const int cur = (k0 >> 5) & 1;
    __syncthreads();                       // drains staged loads for this stage
    if (k0 + 32 < K) stage_in(k0 + 32, cur ^ 1);
    const unsigned short* As = Sh + cur*STG;
    const unsigned short* Bs = As + BM*32;
    bf16x8 af[MI], bfr[4];
#pragma unroll
    for (int mi = 0; mi < MI; mi++) {
      int r = wm + mi*16 + lm;
      af[mi] = *(const bf16x8*)&As[(r*4 + (quad ^ ((r >> 1) & 3))) * 8];
    }
#pragma unroll
    for (int ni = 0; ni < 4; ni++) {
      int r = wn + ni*16 + lm;
      bfr[ni] = *(const bf16x8*)&Bs[(r*4 + (quad ^ ((r >> 1) & 3))) * 8];
    }
#pragma unroll
    for (int mi = 0; mi < MI; mi++)
#pragma unroll
      for (int ni = 0; ni < 4; ni++)
        acc[mi][ni] = __builtin_amdgcn_mfma_f32_16x16x32_bf16(af[mi], bfr[ni], acc[mi][ni], 0, 0, 0);
  }

  if (MODE == 1) {
#pragma unroll
    for (int mi = 0; mi < MI; mi++)
#pragma unroll
      for (int ni = 0; ni < 4; ni++)
#pragma unroll
        for (int r = 0; r < 4; r++) {
          int row = m0 + wm + mi*16 + quad*4 + r;   // C/D: row=(lane>>4)*4+reg
          int col = n0 + wn + ni*16 + lm;           //      col=lane&15
          outF[(size_t)row * N + col] = acc[mi][ni][r] + bias[col];
        }
  } else {
    __syncthreads();
#pragma unroll
    for (int mi = 0; mi < MI; mi++)
#pragma unroll
      for (int ni = 0; ni < 4; ni++)
#pragma unroll
        for (int r = 0; r < 4; r++) {
          int row_l = wm + mi*16 + quad*4 + r;
          int col_l = wn + ni*16 + lm;
          int col = n0 + col_l;
          float v = acc[mi][ni][r] + bias[col];
          if (((col % 192) >> 6) == 0) v *= QSCALE;
          Sh[row_l*CSTR + col_l] = f2bf(v);
        }
    __syncthreads();
    // Q/K: coalesced 16B chunks along e
#pragma unroll
    for (int i = 0; i < 8; i++) {
      int lin = i*256 + tid;
      int row_l = lin >> 4, cc = (lin & 15) * 8;
      int col = n0 + cc;
      int h = col / 192, rr = col - h*192;
      int ty = rr >> 6, e = rr & 63;
      if (ty < 2) {
        uint4 d = *(const uint4*)&Sh[row_l*CSTR + cc];
        int row = m0 + row_l;
        int b = row >> 11, s = row & (SEQ - 1);
        unsigned short* dst = ty ? Kb : Qb;
        *(uint4*)&dst[((size_t)(b*NHEADS + h)*SEQ + s)*HDIM + e] = d;
      }
    }
    // V^T: 16B chunks along s (column reads from Sh; stride 288B = 2-way free)
#pragma unroll
    for (int i = 0; i < 8; i++) {
      int lin = i*256 + tid;
      int col_l = lin & 127, s8 = (lin >> 7) * 8;
      int col = n0 + col_l;
      int h = col / 192, rr = col - h*192;
      if ((rr >> 6) == 2) {
        int e = rr & 63;
        unsigned short tmp[8];
#pragma unroll
        for (int j = 0; j < 8; j++) tmp[j] = Sh[(s8 + j)*CSTR + col_l];
        int row = m0 + s8;
        int b = row >> 11, s = row & (SEQ - 1);
        *(uint4*)&VTb[((size_t)(b*NHEADS + h)*HDIM + e)*SEQ + s] = *(const uint4*)tmp;
      }
    }
  }
}

// Causal flash attention: 512-thread blocks (8 waves), paired 128-query tiles
// {15-pr, pr} -> every block EXACTLY 17 stages of 128 keys (uniform balance,
// half the barriers/serial-chains of the 64-key version). K/V staged in LDS
// shared by 8 waves; single-barrier double-buffered (stage s+1's DMA issued
// right after stage s's barrier). XOR-swizzled LDS for conflict-free b128.
__global__ __launch_bounds__(512) void flash_attn_kernel(
    const unsigned short* __restrict__ Qb,
    const unsigned short* __restrict__ Kb,
    const unsigned short* __restrict__ VTb,
    unsigned short* __restrict__ Ob)
{
  const int tid = threadIdx.x;
  const int wave = tid >> 6, lane = tid & 63;
  const int lm = lane & 15, quad = lane >> 4;
  const int bx = blockIdx.x;                  // 0..31
  const int bh = (bx & 7) * 4 + (bx >> 3);    // XCD i serves bh {4i..4i+3}
  const int pr = blockIdx.y;                  // 0..7
  const int t0 = 15 - pr, t1 = pr;            // paired 128-query tiles
  const int nk0 = t0 + 1;                     // 128-key stages for tile 0
  const int ntot = nk0 + t1 + 1;              // = 17 for every block

  __shared__ __align__(16) unsigned short Ks[2][128*64];  // [buf][key][e]
  __shared__ __align__(16) unsigned short Vs[2][64*128];  // [buf][e][key]
  __shared__ __align__(16) unsigned short Ps[8][16*128];  // per-wave P

  const unsigned short* Qbh  = Qb  + (size_t)bh*SEQ*HDIM;
  const unsigned short* Kbh  = Kb  + (size_t)bh*SEQ*HDIM;
  const unsigned short* VTbh = VTb + (size_t)bh*HDIM*SEQ;
  unsigned short* Pw = &Ps[wave][lm * 128];
  const int sw = lm & 7;

  // staging: K rows 128B (8 chunks), V rows 256B (16 chunks); source chunk
  // XOR-permuted so LDS slot c holds chunk c^(row&7).
  auto stage_in = [&](int k0, int sb) {
#pragma unroll
    for (int i = 0; i < 2; i++) {
      int ch = i*512 + tid;
      int r = ch >> 3, cg = (ch & 7) ^ (r & 7);
      gload16(&Kbh[(size_t)(k0 + r)*HDIM + cg*8], &Ks[sb][ch*8]);
    }
#pragma unroll
    for (int i = 0; i < 2; i++) {
      int ch = i*512 + tid;
      int e = ch >> 4, cg = (ch & 15) ^ (e & 7);
      gload16(&VTbh[(size_t)e*SEQ + k0 + cg*8], &Vs[sb][ch*8]);
    }
  };

  int rowq = t0*128 + wave*16;
  int query = rowq + lm;
  bf16x8 qf[2];
#pragma unroll
  for (int kc = 0; kc < 2; kc++)
    qf[kc] = *(const bf16x8*)&Qbh[(size_t)query*HDIM + kc*32 + quad*8];

  f32x4 o[4] = {};
  float m_run = -1e30f, l_run = 0.f;

  stage_in(0, 0);
  for (int s = 0; s < ntot; s++) {
    const int kt = (s < nk0) ? s : s - nk0;
    const int k0 = kt * 128;
    const int cur = s & 1;
    __syncthreads();                     // staged loads for s drained here
    if (s + 1 < ntot) {
      int sn = s + 1;
      int ktn = (sn < nk0) ? sn : sn - nk0;
      stage_in(ktn * 128, cur ^ 1);      // in flight across this whole stage
    }

    // S^T = K @ Q^T : 8 key-subtiles of 16
    f32x4 sc[8] = {};
#pragma unroll
    for (int kc = 0; kc < 2; kc++)
#pragma unroll
      for (int mi = 0; mi < 8; mi++) {
        int r = mi*16 + lm, cc = kc*4 + quad;
        bf16x8 kf = *(const bf16x8*)&Ks[cur][(r*8 + (cc ^ (r & 7))) * 8];
        sc[mi] = __builtin_amdgcn_mfma_f32_16x16x32_bf16(kf, qf[kc], sc[mi], 0, 0, 0);
      }

    if (k0 + 127 > rowq) {               // causal mask (wave-uniform branch)
#pragma unroll
      for (int mi = 0; mi < 8; mi++)
#pragma unroll
        for (int r = 0; r < 4; r++) {
          int key = k0 + mi*16 + quad*4 + r;
          if (key > query) sc[mi][r] = -1e30f;
        }
    }

    // online softmax (exp2 domain); lane's 32 values all belong to query lm
    float mx = sc[0][0];
#pragma unroll
    for (int mi = 0; mi < 8; mi++)
#pragma unroll
      for (int r = 0; r < 4; r++) mx = fmaxf(mx, sc[mi][r]);
    mx = fmaxf(mx, __shfl_xor(mx, 16, 64));
    mx = fmaxf(mx, __shfl_xor(mx, 32, 64));
    float mnew = fmaxf(m_run, mx);
    float alpha = exp2f(m_run - mnew);
    float p[8][4];
    float rs = 0.f;
#pragma unroll
    for (int mi = 0; mi < 8; mi++)
#pragma unroll
      for (int r = 0; r < 4; r++) {
        p[mi][r] = exp2f(sc[mi][r] - mnew);
        rs += p[mi][r];
      }
    rs += __shfl_xor(rs, 16, 64);
    rs += __shfl_xor(rs, 32, 64);
    l_run = l_run * alpha + rs;
    if (__any(mnew != m_run)) {          // skip rescale when max unchanged
#pragma unroll
      for (int ei = 0; ei < 4; ei++)
#pragma unroll
        for (int r = 0; r < 4; r++) o[ei][r] *= alpha;
    }
    m_run = mnew;

    // P -> wave-private LDS (swizzled b64 writes)
#pragma unroll
    for (int mi = 0; mi < 8; mi++) {
      uint2 u;
      u.x = pack2bf(p[mi][0], p[mi][1]);
      u.y = pack2bf(p[mi][2], p[mi][3]);
      int chunk = (2*mi + (quad >> 1)) ^ sw;
      *(uint2*)&Pw[chunk*8 + (quad & 1)*4] = u;
    }
    asm volatile("s_waitcnt lgkmcnt(0)" ::: "memory");  // same-wave cross-lane

    // O^T += V^T @ P^T : 4 key-chunks of 32
#pragma unroll
    for (int kc = 0; kc < 4; kc++) {
      bf16x8 pf = *(const bf16x8*)&Pw[((kc*4 + quad) ^ sw) * 8];
#pragma unroll
      for (int ei = 0; ei < 4; ei++) {
        int e = ei*16 + lm, cc = kc*4 + quad;
        bf16x8 vf = *(const bf16x8*)&Vs[cur][(e*16 + (cc ^ (e & 7))) * 8];
        o[ei] = __builtin_amdgcn_mfma_f32_16x16x32_bf16(vf, pf, o[ei], 0, 0, 0);
      }
    }

    // tile epilogue (block-uniform branches)
    if (s == nk0 - 1 || s == ntot - 1) {
      float inv = 1.0f / l_run;
      size_t obase = ((size_t)bh*SEQ + query) * HDIM;
#pragma unroll
      for (int ei = 0; ei < 4; ei++) {
        uint2 u;
        u.x = pack2bf(o[ei][0]*inv, o[ei][1]*inv);
        u.y = pack2bf(o[ei][2]*inv, o[ei][3]*inv);
        *(uint2*)&Ob[obase + ei*16 + quad*4] = u;
      }
      if (s == nk0 - 1) {                // switch to second tile
        rowq = t1*128 + wave*16;
        query = rowq + lm;
#pragma unroll
        for (int kc = 0; kc < 2; kc++)
          qf[kc] = *(const bf16x8*)&Qbh[(size_t)query*HDIM + kc*32 + quad*8];
#pragma unroll
        for (int ei = 0; ei < 4; ei++)
#pragma unroll
          for (int r = 0; r < 4; r++) o[ei][r] = 0.f;
        m_run = -1e30f; l_run = 0.f;
      }
    }
  }
}

extern "C" void kernel_launch(void* const* d_in, const int* in_sizes, int n_in,
                              void* d_out, int out_size, void* d_ws, size_t ws_size,
                              hipStream_t stream) {
  const float* x    = (const float*)d_in[0];
  const float* Wqkv = (const float*)d_in[1];
  const float* bqkv = (const float*)d_in[2];
  const float* Wo   = (const float*)d_in[3];
  const float* bo   = (const float*)d_in[4];
  float* out = (float*)d_out;

  char* ws = (char*)d_ws;
  unsigned short* Xbf    = (unsigned short*)(ws);              // 8 MiB
  unsigned short* Wqkvbf = (unsigned short*)(ws + 8388608);    // 6 MiB
  unsigned short* Wobf   = (unsigned short*)(ws + 14680064);   // 2 MiB
  unsigned short* Qb     = (unsigned short*)(ws + 16777216);   // 8 MiB [B,H,S,hd]
  unsigned short* Kb     = (unsigned short*)(ws + 25165824);   // 8 MiB [B,H,S,hd]
  unsigned short* VTb    = (unsigned short*)(ws + 33554432);   // 8 MiB [B,H,hd,S]
  unsigned short* Ob     = (unsigned short*)(ws + 41943040);   // 8 MiB [B,H,S,hd]

  cvt_all_kernel<<<8192, 256, 0, stream>>>(
      (const float4*)x, (const float4*)Wqkv, (const float4*)Wo,
      (ushort4*)Xbf, (ushort4*)Wqkvbf, (ushort4*)Wobf);

  gemm_bt_kernel<0,128><<<dim3(24, 32), 256, 0, stream>>>(
      Xbf, Wqkvbf, bqkv, nullptr, Qb, Kb, VTb, MROWS, NQKV, D_MODEL);

  flash_attn_kernel<<<dim3(32, 8), 512, 0, stream>>>(Qb, Kb, VTb, Ob);

  gemm_bt_kernel<1,64><<<dim3(8, 64), 256, 0, stream>>>(
      Ob, Wobf, bo, out, nullptr, nullptr, nullptr, MROWS, D_MODEL, D_MODEL);
}